// Round 12
// baseline (321.767 us; speedup 1.0000x reference)
//
#include <hip/hip_runtime.h>

#define NNODES 100000
#define NEDGES 800000
#define DIN    256
#define DH     128
#define KCLS   16
#define SCAN_NBLK 98   // ceil(100000/1024)
#define GCH 64         // gram K-chunk rows
#define GRAM_BLK 256   // gram partial blocks

typedef unsigned short u16;
typedef short s16x8 __attribute__((ext_vector_type(8)));
typedef float f32x4 __attribute__((ext_vector_type(4)));

static constexpr float CZ = 0.95f;   // 1 - gamma*l1 + gamma*l2
static constexpr float CS = 0.10f;   // gamma*l1
static constexpr float CT = 0.05f;   // gamma*l2

__device__ __forceinline__ u16 f2b(float f) {           // fp32 -> bf16 RNE
    unsigned u = __builtin_bit_cast(unsigned, f);
    return (u16)((u + 0x7FFFu + ((u >> 16) & 1u)) >> 16);
}
__device__ __forceinline__ float b2f(u16 b) {
    return __builtin_bit_cast(float, ((unsigned)b) << 16);
}
__device__ __forceinline__ s16x8 f2b8(float4 u0, float4 u1) {
    s16x8 v;
    v[0] = (short)f2b(u0.x); v[1] = (short)f2b(u0.y);
    v[2] = (short)f2b(u0.z); v[3] = (short)f2b(u0.w);
    v[4] = (short)f2b(u1.x); v[5] = (short)f2b(u1.y);
    v[6] = (short)f2b(u1.z); v[7] = (short)f2b(u1.w);
    return v;
}

// ---------------- degree / CSR build ----------------

__global__ __launch_bounds__(256) void zero_kernel(int* __restrict__ p) {
    int i = blockIdx.x * 256 + threadIdx.x;
    if (i < NNODES) p[i] = 0;
}

__global__ __launch_bounds__(256) void hist_kernel(const int* __restrict__ col, int* counts) {
    int i = blockIdx.x * 256 + threadIdx.x;
    if (i < NEDGES) atomicAdd(&counts[col[i]], 1);
}

__global__ __launch_bounds__(256) void dinv_kernel(const int* __restrict__ counts, float* dinv) {
    int i = blockIdx.x * 256 + threadIdx.x;
    if (i < NNODES) dinv[i] = rsqrtf((float)(counts[i] + 1));   // +1 self loop
}

__global__ __launch_bounds__(256) void scan1_kernel(const int* __restrict__ counts,
                                                    int* __restrict__ offsets, int* __restrict__ bsum) {
    __shared__ int ls[256];
    const int b = blockIdx.x, t = threadIdx.x;
    const int base = b * 1024 + t * 4;
    int v0 = (base + 0 < NNODES) ? counts[base + 0] : 0;
    int v1 = (base + 1 < NNODES) ? counts[base + 1] : 0;
    int v2 = (base + 2 < NNODES) ? counts[base + 2] : 0;
    int v3 = (base + 3 < NNODES) ? counts[base + 3] : 0;
    ls[t] = v0 + v1 + v2 + v3;
    __syncthreads();
    for (int off = 1; off < 256; off <<= 1) {
        int v = (t >= off) ? ls[t - off] : 0;
        __syncthreads();
        ls[t] += v;
        __syncthreads();
    }
    int excl = (t == 0) ? 0 : ls[t - 1];
    if (t == 255) bsum[b] = ls[255];
    if (base + 0 < NNODES) offsets[base + 0] = excl;
    if (base + 1 < NNODES) offsets[base + 1] = excl + v0;
    if (base + 2 < NNODES) offsets[base + 2] = excl + v0 + v1;
    if (base + 3 < NNODES) offsets[base + 3] = excl + v0 + v1 + v2;
}

// single-block 128-lane exclusive scan of bsum[SCAN_NBLK]
__global__ __launch_bounds__(128) void scan2_kernel(int* bsum) {
    __shared__ int ls[128];
    const int t = threadIdx.x;
    int v = (t < SCAN_NBLK) ? bsum[t] : 0;
    ls[t] = v;
    __syncthreads();
    for (int off = 1; off < 128; off <<= 1) {
        int u = (t >= off) ? ls[t - off] : 0;
        __syncthreads();
        ls[t] += u;
        __syncthreads();
    }
    if (t < SCAN_NBLK) bsum[t] = ls[t] - v;   // exclusive
}

__global__ __launch_bounds__(256) void scan3_kernel(int* __restrict__ offsets, const int* __restrict__ bsum) {
    const int b = blockIdx.x, t = threadIdx.x;
    const int add = bsum[b];
    const int base = b * 1024 + t * 4;
    #pragma unroll
    for (int i = 0; i < 4; ++i)
        if (base + i < NNODES) offsets[base + i] += add;
    if (b == 0 && t == 0) offsets[NNODES] = NEDGES;
}

// only eidx is scattered (4 B/edge)
__global__ __launch_bounds__(256)
void fill_kernel(const int* __restrict__ row, const int* __restrict__ col,
                 const int* __restrict__ offsets, int* __restrict__ cursor,
                 int* __restrict__ eidx) {
    int e = blockIdx.x * 256 + threadIdx.x;
    if (e >= NEDGES) return;
    int c = col[e];
    int p = offsets[c] + atomicAdd(&cursor[c], 1);
    eidx[p] = row[e];
}

// ---------------- prep kernels ----------------

// W fp32 [KD][128] -> Wt bf16 [128][KD]
template<int KD>
__global__ __launch_bounds__(256)
void tr_w_kernel(const float* __restrict__ W, u16* __restrict__ Wt) {
    int idx = blockIdx.x * 256 + threadIdx.x;
    if (idx < 128 * KD) {
        int c = idx / KD, k = idx % KD;
        Wt[idx] = f2b(W[k * 128 + c]);
    }
}

// ---------------- MFMA dense kernels ----------------
// Out[N x 128] = A[N x KD] @ B[KD x 128], Bt bf16 [c][k].
// AF=1: A is fp32, converted to bf16 during staging (fuses cvt_x).
// WS=1: also write Hs = dinv[row]*Out (pre-scaled rows for the gather).
// EPI=1: Bt is G; Out = relu(CZ*Hb + CS*Sb - CT*(A@G) + bias).
// DEPTH-2 software pipeline: chunk k+2's loads issued at iter k, written to
// LDS at iter k+1 -> load->ds_write gap spans a full iteration + barrier
// (counted vmcnt, loads stay in flight across the barrier). Two named
// register slots; loop unrolled x2 so all slot indexing is compile-time.
template<int KD, int EPI, int AF, int WS>
__global__ __launch_bounds__(256, 4)
void mm_bt(const void* __restrict__ Avoid, const u16* __restrict__ Bt,
           u16* __restrict__ Out, const u16* __restrict__ Hb,
           const u16* __restrict__ Sb, const float* __restrict__ bias,
           const float* __restrict__ dinvp, u16* __restrict__ Hs,
           int nrows)
{
    __shared__ __align__(16) u16 as_[2][128 * 40];
    __shared__ __align__(16) u16 bs_[2][128 * 40];
    const int t = threadIdx.x;
    const int w = t >> 6, l = t & 63;
    const int l15 = l & 15, g = l >> 4;
    const int row0 = blockIdx.x * 128;

    const u16*   Ab = (const u16*)Avoid;
    const float* Af = (const float*)Avoid;

    const int sr = t >> 2, so = t & 3;   // staging: row (0..63), k-octet (0..3)
    int arow[2];
    arow[0] = min(row0 + sr,      nrows - 1);
    arow[1] = min(row0 + 64 + sr, nrows - 1);

    f32x4 acc[2][8] = {};
    constexpr int NK = KD / 32;          // 4 or 8 (even, >=2)

    // two register prefetch slots (statically indexed)
    float4 paf0[2][2], paf1[2][2];
    s16x8  pa0[2],     pa1[2];
    s16x8  pb0[2],     pb1[2];

    auto load_chunk = [&](int kc_, float4 (&pafS)[2][2], s16x8 (&paS)[2], s16x8 (&pbS)[2]) {
        const int k0 = kc_ * 32;
        #pragma unroll
        for (int i = 0; i < 2; ++i) {
            if (AF) {
                const float4* p = (const float4*)&Af[(size_t)arow[i] * KD + k0 + so * 8];
                pafS[i][0] = p[0];
                pafS[i][1] = p[1];
            } else {
                paS[i] = *(const s16x8*)&Ab[(size_t)arow[i] * KD + k0 + so * 8];
            }
            pbS[i] = *(const s16x8*)&Bt[(size_t)(sr + i * 64) * KD + k0 + so * 8];
        }
    };
    auto write_chunk = [&](int buf_, float4 (&pafS)[2][2], s16x8 (&paS)[2], s16x8 (&pbS)[2]) {
        #pragma unroll
        for (int i = 0; i < 2; ++i) {
            s16x8 va = AF ? f2b8(pafS[i][0], pafS[i][1]) : paS[i];
            *(s16x8*)&as_[buf_][(sr + i * 64) * 40 + so * 8] = va;
            *(s16x8*)&bs_[buf_][(sr + i * 64) * 40 + so * 8] = pbS[i];
        }
    };
    auto compute = [&](int buf_) {
        s16x8 af0 = *(const s16x8*)&as_[buf_][(w * 32 +      l15) * 40 + g * 8];
        s16x8 af1 = *(const s16x8*)&as_[buf_][(w * 32 + 16 + l15) * 40 + g * 8];
        #pragma unroll
        for (int n = 0; n < 8; ++n) {
            s16x8 bfr = *(const s16x8*)&bs_[buf_][(n * 16 + l15) * 40 + g * 8];
            acc[0][n] = __builtin_amdgcn_mfma_f32_16x16x32_bf16(af0, bfr, acc[0][n], 0, 0, 0);
            acc[1][n] = __builtin_amdgcn_mfma_f32_16x16x32_bf16(af1, bfr, acc[1][n], 0, 0, 0);
        }
    };

    // prologue: chunk0 -> LDS0 directly; chunk1 loads left in flight
    load_chunk(0, paf0, pa0, pb0);
    write_chunk(0, paf0, pa0, pb0);
    load_chunk(1, paf1, pa1, pb1);
    __syncthreads();

    for (int kc = 0; kc < NK; kc += 2) {
        // even sub-iter: compute LDS0, write chunk kc+1 (slot1) -> LDS1
        if (kc + 2 < NK) load_chunk(kc + 2, paf0, pa0, pb0);
        compute(0);
        write_chunk(1, paf1, pa1, pb1);
        __syncthreads();
        // odd sub-iter: compute LDS1, write chunk kc+2 (slot0) -> LDS0
        if (kc + 3 < NK) load_chunk(kc + 3, paf1, pa1, pb1);
        compute(1);
        if (kc + 2 < NK) write_chunk(0, paf0, pa0, pb0);
        __syncthreads();
    }

    float bv[8];
    if (EPI) {
        #pragma unroll
        for (int n = 0; n < 8; ++n) bv[n] = bias[n * 16 + l15];
    }
    #pragma unroll
    for (int m = 0; m < 2; ++m) {
        #pragma unroll
        for (int j = 0; j < 4; ++j) {
            int grow = row0 + w * 32 + m * 16 + g * 4 + j;
            if (grow < nrows) {
                size_t base = (size_t)grow * 128;
                float dv = WS ? dinvp[grow] : 0.f;
                #pragma unroll
                for (int n = 0; n < 8; ++n) {
                    int col = n * 16 + l15;
                    float v = acc[m][n][j];
                    if (EPI) {
                        float h = b2f(Hb[base + col]);
                        float s = b2f(Sb[base + col]);
                        v = fmaxf(CZ * h + CS * s - CT * v + bv[n], 0.f);
                    }
                    Out[base + col] = f2b(v);
                    if (WS) Hs[base + col] = f2b(dv * v);
                }
            }
        }
    }
}

// ---------------- fused gram + gather ----------------
// blocks [0, GRAM_BLK): gram partials P[b] = sum of 64-row chunks of Hb^T Hb
//   (chunk stride GRAM_BLK — constant), single-buffered 16 KB tile.
// blocks [GRAM_BLK, ...): gather S[c] = dinv[c] * (Hs[c] + sum_{e->c} Hs[r])
//   where Hs = dinv*H was pre-scaled by the producer mm.
__global__ __launch_bounds__(256)
void gram_gather(const u16* __restrict__ Hb, const u16* __restrict__ Hsb,
                 const float* __restrict__ dinv,
                 const int* __restrict__ offsets, const int* __restrict__ eidx,
                 float* __restrict__ P, u16* __restrict__ Sb, int nrows)
{
    __shared__ __align__(16) u16 ht[128 * GCH];  // ht[c*GCH + (k ^ ((c&7)<<3))]
    const int t = threadIdx.x;

    if (blockIdx.x < GRAM_BLK) {
        // ---------------- gram ----------------
        const int bid = blockIdx.x;
        const int w = t >> 6, l = t & 63;
        const int l15 = l & 15, g = l >> 4;
        const int nch = (nrows + GCH - 1) / GCH;

        f32x4 acc[2][8] = {};
        const int sr = t >> 2, sq = t & 3;   // staging: row sr, col-quarter sq

        for (int ch = bid; ch < nch; ch += GRAM_BLK) {
            {   // stage chunk
                int gr = ch * GCH + sr;
                #pragma unroll
                for (int i4 = 0; i4 < 4; ++i4) {
                    int c0 = sq * 32 + i4 * 8;
                    s16x8 v = {};
                    if (gr < nrows) v = *(const s16x8*)&Hb[(size_t)gr * DH + c0];
                    #pragma unroll
                    for (int i = 0; i < 8; ++i) {
                        int c = c0 + i;
                        ht[c * GCH + (sr ^ ((c & 7) << 3))] = (u16)v[i];
                    }
                }
            }
            __syncthreads();
            #pragma unroll
            for (int ks = 0; ks < 2; ++ks) {
                const int kx = (ks * 32 + g * 8) ^ ((l & 7) << 3);
                s16x8 a0 = *(const s16x8*)&ht[(w * 32 +      l15) * GCH + kx];
                s16x8 a1 = *(const s16x8*)&ht[(w * 32 + 16 + l15) * GCH + kx];
                #pragma unroll
                for (int n = 0; n < 8; ++n) {
                    s16x8 bfr = *(const s16x8*)&ht[(n * 16 + l15) * GCH + kx];
                    acc[0][n] = __builtin_amdgcn_mfma_f32_16x16x32_bf16(a0, bfr, acc[0][n], 0, 0, 0);
                    acc[1][n] = __builtin_amdgcn_mfma_f32_16x16x32_bf16(a1, bfr, acc[1][n], 0, 0, 0);
                }
            }
            __syncthreads();
        }

        float* Pb = P + (size_t)bid * (DH * DH);
        #pragma unroll
        for (int m = 0; m < 2; ++m)
            #pragma unroll
            for (int j = 0; j < 4; ++j) {
                int prow = w * 32 + m * 16 + g * 4 + j;
                #pragma unroll
                for (int n = 0; n < 8; ++n)
                    Pb[prow * DH + n * 16 + l15] = acc[m][n][j];
            }
    } else {
        // ---------------- gather ----------------
        const int grp = t >> 4;           // 16 groups per block
        const int gl  = t & 15;           // lane within group
        const int node = (blockIdx.x - GRAM_BLK) * 16 + grp;
        if (node >= NNODES) return;
        const s16x8* Hs8 = (const s16x8*)Hsb;   // 16 s16x8 per row
        const float d = dinv[node];
        s16x8 hv = Hs8[(size_t)node * 16 + gl];
        float a[8];
        #pragma unroll
        for (int i = 0; i < 8; ++i) a[i] = b2f((u16)hv[i]);
        int p = offsets[node];
        const int e = offsets[node + 1];
        for (; p + 3 < e; p += 4) {
            int r0 = eidx[p], r1 = eidx[p + 1], r2 = eidx[p + 2], r3 = eidx[p + 3];
            s16x8 h0 = Hs8[(size_t)r0 * 16 + gl];
            s16x8 h1 = Hs8[(size_t)r1 * 16 + gl];
            s16x8 h2 = Hs8[(size_t)r2 * 16 + gl];
            s16x8 h3 = Hs8[(size_t)r3 * 16 + gl];
            #pragma unroll
            for (int i = 0; i < 8; ++i) a[i] += b2f((u16)h0[i]);
            #pragma unroll
            for (int i = 0; i < 8; ++i) a[i] += b2f((u16)h1[i]);
            #pragma unroll
            for (int i = 0; i < 8; ++i) a[i] += b2f((u16)h2[i]);
            #pragma unroll
            for (int i = 0; i < 8; ++i) a[i] += b2f((u16)h3[i]);
        }
        for (; p < e; ++p) {
            int r0 = eidx[p];
            s16x8 h0 = Hs8[(size_t)r0 * 16 + gl];
            #pragma unroll
            for (int i = 0; i < 8; ++i) a[i] += b2f((u16)h0[i]);
        }
        s16x8 o;
        #pragma unroll
        for (int i = 0; i < 8; ++i) o[i] = (short)f2b(d * a[i]);
        ((s16x8*)Sb)[(size_t)node * 16 + gl] = o;
    }
}

// deterministic reduce of partials -> G bf16 (G is symmetric: no transpose needed)
__global__ __launch_bounds__(256)
void gram_reduce(const float* __restrict__ P, u16* __restrict__ Gb) {
    int idx = blockIdx.x * 256 + threadIdx.x;   // grid 64 -> 16384
    float s = 0.f;
    #pragma unroll 8
    for (int p = 0; p < GRAM_BLK; ++p)
        s += P[(size_t)p * (DH * DH) + idx];
    Gb[idx] = f2b(s);
}

// FC + log_softmax via MFMA: logits = Xb @ Wf + bf, then in-register softmax.
__global__ __launch_bounds__(256)
void fc_mfma(const u16* __restrict__ Xb, const float* __restrict__ Wf,
             const float* __restrict__ bf, float* __restrict__ out, int nrows)
{
    __shared__ __align__(16) u16 wt[KCLS * DH];   // wt[c*128 + (k ^ ((c&7)<<3))]
    const int t = threadIdx.x;
    const int w = t >> 6, l = t & 63;
    const int l15 = l & 15, g = l >> 4;
    const int row0 = blockIdx.x * 128 + w * 32;

    for (int idx = t; idx < KCLS * DH; idx += 256) {
        int c = idx >> 7, k = idx & 127;
        wt[c * DH + (k ^ ((c & 7) << 3))] = f2b(Wf[k * KCLS + c]);
    }
    __syncthreads();

    int r[2];
    r[0] = min(row0 + l15,      nrows - 1);
    r[1] = min(row0 + 16 + l15, nrows - 1);

    f32x4 acc[2] = {};
    #pragma unroll
    for (int k0 = 0; k0 < DH; k0 += 32) {
        s16x8 a0 = *(const s16x8*)&Xb[(size_t)r[0] * DH + k0 + g * 8];
        s16x8 a1 = *(const s16x8*)&Xb[(size_t)r[1] * DH + k0 + g * 8];
        s16x8 bfr = *(const s16x8*)&wt[l15 * DH + ((k0 + g * 8) ^ ((l & 7) << 3))];
        acc[0] = __builtin_amdgcn_mfma_f32_16x16x32_bf16(a0, bfr, acc[0], 0, 0, 0);
        acc[1] = __builtin_amdgcn_mfma_f32_16x16x32_bf16(a1, bfr, acc[1], 0, 0, 0);
    }

    const float bias = bf[l15];
    #pragma unroll
    for (int m = 0; m < 2; ++m) {
        #pragma unroll
        for (int j = 0; j < 4; ++j) {
            int grow = row0 + m * 16 + g * 4 + j;
            float v = acc[m][j] + bias;
            float mx = v;
            #pragma unroll
            for (int o = 8; o >= 1; o >>= 1)
                mx = fmaxf(mx, __shfl_xor(mx, o));
            float e = expf(v - mx);
            float ssum = e;
            #pragma unroll
            for (int o = 8; o >= 1; o >>= 1)
                ssum += __shfl_xor(ssum, o);
            if (grow < nrows)
                out[(size_t)grow * KCLS + l15] = v - mx - logf(ssum);
        }
    }
}

extern "C" void kernel_launch(void* const* d_in, const int* in_sizes, int n_in,
                              void* d_out, int out_size, void* d_ws, size_t ws_size,
                              hipStream_t stream) {
    const float* x  = (const float*)d_in[0];
    const int*   ei = (const int*)d_in[1];
    const float* W1 = (const float*)d_in[2];
    const float* b1 = (const float*)d_in[3];
    const float* W2 = (const float*)d_in[4];
    const float* b2 = (const float*)d_in[5];
    const float* Wf = (const float*)d_in[6];
    const float* bf = (const float*)d_in[7];
    float* out = (float*)d_out;

    const int* row = ei;            // edge_index[0] = source
    const int* col = ei + NEDGES;   // edge_index[1] = target

    float* dinv    = (float*)d_ws;                       // 102400 f
    float* P       = dinv + 102400;                      // 256*16384 f
    int*   counts  = (int*)(P + (size_t)GRAM_BLK * DH * DH);  // 102400
    int*   offsets = counts + 102400;                    // 102656
    int*   bsum    = offsets + 102656;                   // 128
    int*   eidx    = bsum + 128;                         // E
    u16*   B0b     = (u16*)(eidx + NEDGES);              // N*128
    u16*   B1b     = B0b + (size_t)NNODES * DH;          // N*128
    u16*   Sb      = B1b + (size_t)NNODES * DH;          // N*128
    u16*   Hsb     = Sb + (size_t)NNODES * DH;           // N*128 (pre-scaled rows)
    u16*   W1t     = Hsb + (size_t)NNODES * DH;          // 128*256
    u16*   W2t     = W1t + 128 * DIN;                    // 128*128
    u16*   Gb      = W2t + 128 * DH;                     // 128*128

    dim3 b256(256);
    const int gN  = (NNODES + 255) / 256;
    const int gE  = (NEDGES + 255) / 256;
    const int gMM = (NNODES + 127) / 128;                // 782
    const int gGG = GRAM_BLK + (NNODES + 15) / 16;       // fused gram+gather

    // ---- degrees + CSR build + weight prep ----
    zero_kernel<<<gN, b256, 0, stream>>>(counts);
    hist_kernel<<<gE, b256, 0, stream>>>(col, counts);
    dinv_kernel<<<gN, b256, 0, stream>>>(counts, dinv);
    scan1_kernel<<<SCAN_NBLK, b256, 0, stream>>>(counts, offsets, bsum);
    scan2_kernel<<<1, 128, 0, stream>>>(bsum);
    scan3_kernel<<<SCAN_NBLK, b256, 0, stream>>>(offsets, bsum);
    zero_kernel<<<gN, b256, 0, stream>>>(counts);   // reuse as cursor
    fill_kernel<<<gE, b256, 0, stream>>>(row, col, offsets, counts, eidx);
    tr_w_kernel<DIN><<<(128 * DIN + 255) / 256, b256, 0, stream>>>(W1, W1t);
    tr_w_kernel<DH><<<(128 * DH + 255) / 256, b256, 0, stream>>>(W2, W2t);

    // ---- layer 1 ----
    mm_bt<DIN, 0, 1, 1><<<gMM, b256, 0, stream>>>(x, W1t, B0b, nullptr, nullptr, nullptr, dinv, Hsb, NNODES);
    gram_gather<<<gGG, b256, 0, stream>>>(B0b, Hsb, dinv, offsets, eidx, P, Sb, NNODES);
    gram_reduce<<<64, b256, 0, stream>>>(P, Gb);
    mm_bt<DH, 1, 0, 0><<<gMM, b256, 0, stream>>>(B0b, Gb, B1b, B0b, Sb, b1, nullptr, nullptr, NNODES);

    // ---- layer 2 ----
    mm_bt<DH, 0, 0, 1><<<gMM, b256, 0, stream>>>(B1b, W2t, B0b, nullptr, nullptr, nullptr, dinv, Hsb, NNODES);
    gram_gather<<<gGG, b256, 0, stream>>>(B0b, Hsb, dinv, offsets, eidx, P, Sb, NNODES);
    gram_reduce<<<64, b256, 0, stream>>>(P, Gb);
    mm_bt<DH, 1, 0, 0><<<gMM, b256, 0, stream>>>(B0b, Gb, B1b, B0b, Sb, b2, nullptr, nullptr, NNODES);

    // ---- fc + log_softmax (MFMA) ----
    fc_mfma<<<gMM, b256, 0, stream>>>(B1b, Wf, bf, out, NNODES);
}

// Round 13
// 281.304 us; speedup vs baseline: 1.1438x; 1.1438x over previous
//
#include <hip/hip_runtime.h>

#define NNODES 100000
#define NEDGES 800000
#define DIN    256
#define DH     128
#define KCLS   16
#define SCAN_NBLK 98   // ceil(100000/1024)
#define GCH 64         // gram K-chunk rows
#define GRAM_BLK 256   // gram partial blocks

typedef unsigned short u16;
typedef short s16x8 __attribute__((ext_vector_type(8)));
typedef float f32x4 __attribute__((ext_vector_type(4)));

static constexpr float CZ = 0.95f;   // 1 - gamma*l1 + gamma*l2
static constexpr float CS = 0.10f;   // gamma*l1
static constexpr float CT = 0.05f;   // gamma*l2

__device__ __forceinline__ u16 f2b(float f) {           // fp32 -> bf16 RNE
    unsigned u = __builtin_bit_cast(unsigned, f);
    return (u16)((u + 0x7FFFu + ((u >> 16) & 1u)) >> 16);
}
__device__ __forceinline__ float b2f(u16 b) {
    return __builtin_bit_cast(float, ((unsigned)b) << 16);
}
__device__ __forceinline__ s16x8 f2b8(float4 u0, float4 u1) {
    s16x8 v;
    v[0] = (short)f2b(u0.x); v[1] = (short)f2b(u0.y);
    v[2] = (short)f2b(u0.z); v[3] = (short)f2b(u0.w);
    v[4] = (short)f2b(u1.x); v[5] = (short)f2b(u1.y);
    v[6] = (short)f2b(u1.z); v[7] = (short)f2b(u1.w);
    return v;
}

// ---------------- degree / CSR build ----------------

__global__ __launch_bounds__(256) void zero_kernel(int* __restrict__ p) {
    int i = blockIdx.x * 256 + threadIdx.x;
    if (i < NNODES) p[i] = 0;
}

// histogram + per-edge rank (order within its target's segment)
__global__ __launch_bounds__(256)
void hist_kernel(const int* __restrict__ col, int* __restrict__ counts,
                 int* __restrict__ rank) {
    int i = blockIdx.x * 256 + threadIdx.x;
    if (i < NEDGES) rank[i] = atomicAdd(&counts[col[i]], 1);
}

__global__ __launch_bounds__(256) void dinv_kernel(const int* __restrict__ counts, float* dinv) {
    int i = blockIdx.x * 256 + threadIdx.x;
    if (i < NNODES) dinv[i] = rsqrtf((float)(counts[i] + 1));   // +1 self loop
}

__global__ __launch_bounds__(256) void scan1_kernel(const int* __restrict__ counts,
                                                    int* __restrict__ offsets, int* __restrict__ bsum) {
    __shared__ int ls[256];
    const int b = blockIdx.x, t = threadIdx.x;
    const int base = b * 1024 + t * 4;
    int v0 = (base + 0 < NNODES) ? counts[base + 0] : 0;
    int v1 = (base + 1 < NNODES) ? counts[base + 1] : 0;
    int v2 = (base + 2 < NNODES) ? counts[base + 2] : 0;
    int v3 = (base + 3 < NNODES) ? counts[base + 3] : 0;
    ls[t] = v0 + v1 + v2 + v3;
    __syncthreads();
    for (int off = 1; off < 256; off <<= 1) {
        int v = (t >= off) ? ls[t - off] : 0;
        __syncthreads();
        ls[t] += v;
        __syncthreads();
    }
    int excl = (t == 0) ? 0 : ls[t - 1];
    if (t == 255) bsum[b] = ls[255];
    if (base + 0 < NNODES) offsets[base + 0] = excl;
    if (base + 1 < NNODES) offsets[base + 1] = excl + v0;
    if (base + 2 < NNODES) offsets[base + 2] = excl + v0 + v1;
    if (base + 3 < NNODES) offsets[base + 3] = excl + v0 + v1 + v2;
}

// single-block 128-lane exclusive scan of bsum[SCAN_NBLK]
__global__ __launch_bounds__(128) void scan2_kernel(int* bsum) {
    __shared__ int ls[128];
    const int t = threadIdx.x;
    int v = (t < SCAN_NBLK) ? bsum[t] : 0;
    ls[t] = v;
    __syncthreads();
    for (int off = 1; off < 128; off <<= 1) {
        int u = (t >= off) ? ls[t - off] : 0;
        __syncthreads();
        ls[t] += u;
        __syncthreads();
    }
    if (t < SCAN_NBLK) bsum[t] = ls[t] - v;   // exclusive
}

__global__ __launch_bounds__(256) void scan3_kernel(int* __restrict__ offsets, const int* __restrict__ bsum) {
    const int b = blockIdx.x, t = threadIdx.x;
    const int add = bsum[b];
    const int base = b * 1024 + t * 4;
    #pragma unroll
    for (int i = 0; i < 4; ++i)
        if (base + i < NNODES) offsets[base + i] += add;
    if (b == 0 && t == 0) offsets[NNODES] = NEDGES;
}

// atomic-free fill: position = offsets[col] + rank (precomputed in hist)
__global__ __launch_bounds__(256)
void fill_kernel(const int* __restrict__ row, const int* __restrict__ col,
                 const int* __restrict__ offsets, const int* __restrict__ rank,
                 int* __restrict__ eidx) {
    int e = blockIdx.x * 256 + threadIdx.x;
    if (e >= NEDGES) return;
    eidx[offsets[col[e]] + rank[e]] = row[e];
}

// ---------------- prep kernels ----------------

// W fp32 [KD][128] -> Wt bf16 [128][KD]
template<int KD>
__global__ __launch_bounds__(256)
void tr_w_kernel(const float* __restrict__ W, u16* __restrict__ Wt) {
    int idx = blockIdx.x * 256 + threadIdx.x;
    if (idx < 128 * KD) {
        int c = idx / KD, k = idx % KD;
        Wt[idx] = f2b(W[k * 128 + c]);
    }
}

// ---------------- MFMA dense kernels ----------------
// Out[N x 128] = A[N x KD] @ B[KD x 128], Bt bf16 [c][k].
// 64-row tile, single-buffered 15.4 KB LDS -> 8 blocks/CU (thread-capped),
// 1563 blocks (~6/CU): cross-block TLP hides staging latency (m114 mechanism;
// explicit source pipelining is drained at barriers by the compiler).
// AF=1: A fp32, converted during staging. WS=1: also write Hs = dinv*Out.
// EPI=1: Bt is G; Out = relu(CZ*Hb + CS*Sb - CT*(A@G) + bias).
template<int KD, int EPI, int AF, int WS>
__global__ __launch_bounds__(256)
void mm_bt(const void* __restrict__ Avoid, const u16* __restrict__ Bt,
           u16* __restrict__ Out, const u16* __restrict__ Hb,
           const u16* __restrict__ Sb, const float* __restrict__ bias,
           const float* __restrict__ dinvp, u16* __restrict__ Hs,
           int nrows)
{
    __shared__ __align__(16) u16 as_[64 * 40];
    __shared__ __align__(16) u16 bs_[128 * 40];
    const int t = threadIdx.x;
    const int w = t >> 6, l = t & 63;
    const int l15 = l & 15, g = l >> 4;
    const int row0 = blockIdx.x * 64;

    const u16*   Ab = (const u16*)Avoid;
    const float* Af = (const float*)Avoid;

    const int sr = t >> 2, so = t & 3;   // staging: row 0..63, k-octet 0..3
    const int srow = min(row0 + sr, nrows - 1);

    f32x4 acc[8] = {};
    constexpr int NK = KD / 32;

    for (int kc = 0; kc < NK; ++kc) {
        const int k0 = kc * 32;
        // issue loads before the barrier (overlap with previous chunk's MFMAs)
        s16x8 va;
        if (AF) {
            const float4* p = (const float4*)&Af[(size_t)srow * KD + k0 + so * 8];
            va = f2b8(p[0], p[1]);
        } else {
            va = *(const s16x8*)&Ab[(size_t)srow * KD + k0 + so * 8];
        }
        s16x8 vb0 = *(const s16x8*)&Bt[(size_t)sr        * KD + k0 + so * 8];
        s16x8 vb1 = *(const s16x8*)&Bt[(size_t)(sr + 64) * KD + k0 + so * 8];
        if (kc) __syncthreads();          // previous compute done reading LDS
        *(s16x8*)&as_[sr * 40 + so * 8]        = va;
        *(s16x8*)&bs_[sr * 40 + so * 8]        = vb0;
        *(s16x8*)&bs_[(sr + 64) * 40 + so * 8] = vb1;
        __syncthreads();
        s16x8 af = *(const s16x8*)&as_[(w * 16 + l15) * 40 + g * 8];
        #pragma unroll
        for (int n = 0; n < 8; ++n) {
            s16x8 bfr = *(const s16x8*)&bs_[(n * 16 + l15) * 40 + g * 8];
            acc[n] = __builtin_amdgcn_mfma_f32_16x16x32_bf16(af, bfr, acc[n], 0, 0, 0);
        }
    }

    float bv[8];
    if (EPI) {
        #pragma unroll
        for (int n = 0; n < 8; ++n) bv[n] = bias[n * 16 + l15];
    }
    #pragma unroll
    for (int j = 0; j < 4; ++j) {
        int grow = row0 + w * 16 + g * 4 + j;
        if (grow < nrows) {
            size_t base = (size_t)grow * 128;
            float dv = WS ? dinvp[grow] : 0.f;
            #pragma unroll
            for (int n = 0; n < 8; ++n) {
                int col = n * 16 + l15;
                float v = acc[n][j];
                if (EPI) {
                    float h = b2f(Hb[base + col]);
                    float s = b2f(Sb[base + col]);
                    v = fmaxf(CZ * h + CS * s - CT * v + bv[n], 0.f);
                }
                Out[base + col] = f2b(v);
                if (WS) Hs[base + col] = f2b(dv * v);
            }
        }
    }
}

// ---------------- fused gram + gather ----------------
// blocks [0, GRAM_BLK): gram partials P[b] = sum of 64-row chunks of Hb^T Hb
//   (chunk stride GRAM_BLK — constant), single-buffered 16 KB tile.
// blocks [GRAM_BLK, ...): gather S[c] = dinv[c] * (Hs[c] + sum_{e->c} Hs[r])
//   where Hs = dinv*H was pre-scaled by the producer mm.
__global__ __launch_bounds__(256)
void gram_gather(const u16* __restrict__ Hb, const u16* __restrict__ Hsb,
                 const float* __restrict__ dinv,
                 const int* __restrict__ offsets, const int* __restrict__ eidx,
                 float* __restrict__ P, u16* __restrict__ Sb, int nrows)
{
    __shared__ __align__(16) u16 ht[128 * GCH];  // ht[c*GCH + (k ^ ((c&7)<<3))]
    const int t = threadIdx.x;

    if (blockIdx.x < GRAM_BLK) {
        // ---------------- gram ----------------
        const int bid = blockIdx.x;
        const int w = t >> 6, l = t & 63;
        const int l15 = l & 15, g = l >> 4;
        const int nch = (nrows + GCH - 1) / GCH;

        f32x4 acc[2][8] = {};
        const int sr = t >> 2, sq = t & 3;   // staging: row sr, col-quarter sq

        for (int ch = bid; ch < nch; ch += GRAM_BLK) {
            {   // stage chunk
                int gr = ch * GCH + sr;
                #pragma unroll
                for (int i4 = 0; i4 < 4; ++i4) {
                    int c0 = sq * 32 + i4 * 8;
                    s16x8 v = {};
                    if (gr < nrows) v = *(const s16x8*)&Hb[(size_t)gr * DH + c0];
                    #pragma unroll
                    for (int i = 0; i < 8; ++i) {
                        int c = c0 + i;
                        ht[c * GCH + (sr ^ ((c & 7) << 3))] = (u16)v[i];
                    }
                }
            }
            __syncthreads();
            #pragma unroll
            for (int ks = 0; ks < 2; ++ks) {
                const int kx = (ks * 32 + g * 8) ^ ((l & 7) << 3);
                s16x8 a0 = *(const s16x8*)&ht[(w * 32 +      l15) * GCH + kx];
                s16x8 a1 = *(const s16x8*)&ht[(w * 32 + 16 + l15) * GCH + kx];
                #pragma unroll
                for (int n = 0; n < 8; ++n) {
                    s16x8 bfr = *(const s16x8*)&ht[(n * 16 + l15) * GCH + kx];
                    acc[0][n] = __builtin_amdgcn_mfma_f32_16x16x32_bf16(a0, bfr, acc[0][n], 0, 0, 0);
                    acc[1][n] = __builtin_amdgcn_mfma_f32_16x16x32_bf16(a1, bfr, acc[1][n], 0, 0, 0);
                }
            }
            __syncthreads();
        }

        float* Pb = P + (size_t)bid * (DH * DH);
        #pragma unroll
        for (int m = 0; m < 2; ++m)
            #pragma unroll
            for (int j = 0; j < 4; ++j) {
                int prow = w * 32 + m * 16 + g * 4 + j;
                #pragma unroll
                for (int n = 0; n < 8; ++n)
                    Pb[prow * DH + n * 16 + l15] = acc[m][n][j];
            }
    } else {
        // ---------------- gather ----------------
        const int grp = t >> 4;           // 16 groups per block
        const int gl  = t & 15;           // lane within group
        const int node = (blockIdx.x - GRAM_BLK) * 16 + grp;
        if (node >= NNODES) return;
        const s16x8* Hs8 = (const s16x8*)Hsb;   // 16 s16x8 per row
        const float d = dinv[node];
        s16x8 hv = Hs8[(size_t)node * 16 + gl];
        float a[8];
        #pragma unroll
        for (int i = 0; i < 8; ++i) a[i] = b2f((u16)hv[i]);
        int p = offsets[node];
        const int e = offsets[node + 1];
        for (; p + 3 < e; p += 4) {
            int r0 = eidx[p], r1 = eidx[p + 1], r2 = eidx[p + 2], r3 = eidx[p + 3];
            s16x8 h0 = Hs8[(size_t)r0 * 16 + gl];
            s16x8 h1 = Hs8[(size_t)r1 * 16 + gl];
            s16x8 h2 = Hs8[(size_t)r2 * 16 + gl];
            s16x8 h3 = Hs8[(size_t)r3 * 16 + gl];
            #pragma unroll
            for (int i = 0; i < 8; ++i) a[i] += b2f((u16)h0[i]);
            #pragma unroll
            for (int i = 0; i < 8; ++i) a[i] += b2f((u16)h1[i]);
            #pragma unroll
            for (int i = 0; i < 8; ++i) a[i] += b2f((u16)h2[i]);
            #pragma unroll
            for (int i = 0; i < 8; ++i) a[i] += b2f((u16)h3[i]);
        }
        for (; p < e; ++p) {
            int r0 = eidx[p];
            s16x8 h0 = Hs8[(size_t)r0 * 16 + gl];
            #pragma unroll
            for (int i = 0; i < 8; ++i) a[i] += b2f((u16)h0[i]);
        }
        s16x8 o;
        #pragma unroll
        for (int i = 0; i < 8; ++i) o[i] = (short)f2b(d * a[i]);
        ((s16x8*)Sb)[(size_t)node * 16 + gl] = o;
    }
}

// deterministic reduce of partials -> G bf16 (G is symmetric: no transpose needed)
__global__ __launch_bounds__(256)
void gram_reduce(const float* __restrict__ P, u16* __restrict__ Gb) {
    int idx = blockIdx.x * 256 + threadIdx.x;   // grid 64 -> 16384
    float s = 0.f;
    #pragma unroll 8
    for (int p = 0; p < GRAM_BLK; ++p)
        s += P[(size_t)p * (DH * DH) + idx];
    Gb[idx] = f2b(s);
}

// FC + log_softmax via MFMA: logits = Xb @ Wf + bf, then in-register softmax.
__global__ __launch_bounds__(256)
void fc_mfma(const u16* __restrict__ Xb, const float* __restrict__ Wf,
             const float* __restrict__ bf, float* __restrict__ out, int nrows)
{
    __shared__ __align__(16) u16 wt[KCLS * DH];   // wt[c*128 + (k ^ ((c&7)<<3))]
    const int t = threadIdx.x;
    const int w = t >> 6, l = t & 63;
    const int l15 = l & 15, g = l >> 4;
    const int row0 = blockIdx.x * 128 + w * 32;

    for (int idx = t; idx < KCLS * DH; idx += 256) {
        int c = idx >> 7, k = idx & 127;
        wt[c * DH + (k ^ ((c & 7) << 3))] = f2b(Wf[k * KCLS + c]);
    }
    __syncthreads();

    int r[2];
    r[0] = min(row0 + l15,      nrows - 1);
    r[1] = min(row0 + 16 + l15, nrows - 1);

    f32x4 acc[2] = {};
    #pragma unroll
    for (int k0 = 0; k0 < DH; k0 += 32) {
        s16x8 a0 = *(const s16x8*)&Xb[(size_t)r[0] * DH + k0 + g * 8];
        s16x8 a1 = *(const s16x8*)&Xb[(size_t)r[1] * DH + k0 + g * 8];
        s16x8 bfr = *(const s16x8*)&wt[l15 * DH + ((k0 + g * 8) ^ ((l & 7) << 3))];
        acc[0] = __builtin_amdgcn_mfma_f32_16x16x32_bf16(a0, bfr, acc[0], 0, 0, 0);
        acc[1] = __builtin_amdgcn_mfma_f32_16x16x32_bf16(a1, bfr, acc[1], 0, 0, 0);
    }

    const float bias = bf[l15];
    #pragma unroll
    for (int m = 0; m < 2; ++m) {
        #pragma unroll
        for (int j = 0; j < 4; ++j) {
            int grow = row0 + m * 16 + g * 4 + j;
            float v = acc[m][j] + bias;
            float mx = v;
            #pragma unroll
            for (int o = 8; o >= 1; o >>= 1)
                mx = fmaxf(mx, __shfl_xor(mx, o));
            float e = expf(v - mx);
            float ssum = e;
            #pragma unroll
            for (int o = 8; o >= 1; o >>= 1)
                ssum += __shfl_xor(ssum, o);
            if (grow < nrows)
                out[(size_t)grow * KCLS + l15] = v - mx - logf(ssum);
        }
    }
}

extern "C" void kernel_launch(void* const* d_in, const int* in_sizes, int n_in,
                              void* d_out, int out_size, void* d_ws, size_t ws_size,
                              hipStream_t stream) {
    const float* x  = (const float*)d_in[0];
    const int*   ei = (const int*)d_in[1];
    const float* W1 = (const float*)d_in[2];
    const float* b1 = (const float*)d_in[3];
    const float* W2 = (const float*)d_in[4];
    const float* b2 = (const float*)d_in[5];
    const float* Wf = (const float*)d_in[6];
    const float* bf = (const float*)d_in[7];
    float* out = (float*)d_out;

    const int* row = ei;            // edge_index[0] = source
    const int* col = ei + NEDGES;   // edge_index[1] = target

    float* dinv    = (float*)d_ws;                       // 102400 f
    float* P       = dinv + 102400;                      // 256*16384 f
    int*   counts  = (int*)(P + (size_t)GRAM_BLK * DH * DH);  // 102400
    int*   offsets = counts + 102400;                    // 102656
    int*   bsum    = offsets + 102656;                   // 128
    int*   eidx    = bsum + 128;                         // E
    int*   rank    = eidx + NEDGES;                      // E
    u16*   B0b     = (u16*)(rank + NEDGES);              // N*128
    u16*   B1b     = B0b + (size_t)NNODES * DH;          // N*128
    u16*   Sb      = B1b + (size_t)NNODES * DH;          // N*128
    u16*   Hsb     = Sb + (size_t)NNODES * DH;           // N*128 (pre-scaled rows)
    u16*   W1t     = Hsb + (size_t)NNODES * DH;          // 128*256
    u16*   W2t     = W1t + 128 * DIN;                    // 128*128
    u16*   Gb      = W2t + 128 * DH;                     // 128*128

    dim3 b256(256);
    const int gN   = (NNODES + 255) / 256;
    const int gE   = (NEDGES + 255) / 256;
    const int gMM  = (NNODES + 63) / 64;                 // 1563 (64-row tiles)
    const int gFC  = (NNODES + 127) / 128;               // fc grid
    const int gGG  = GRAM_BLK + (NNODES + 15) / 16;      // fused gram+gather

    // ---- degrees + CSR build + weight prep ----
    zero_kernel<<<gN, b256, 0, stream>>>(counts);
    hist_kernel<<<gE, b256, 0, stream>>>(col, counts, rank);
    dinv_kernel<<<gN, b256, 0, stream>>>(counts, dinv);
    scan1_kernel<<<SCAN_NBLK, b256, 0, stream>>>(counts, offsets, bsum);
    scan2_kernel<<<1, 128, 0, stream>>>(bsum);
    scan3_kernel<<<SCAN_NBLK, b256, 0, stream>>>(offsets, bsum);
    fill_kernel<<<gE, b256, 0, stream>>>(row, col, offsets, rank, eidx);
    tr_w_kernel<DIN><<<(128 * DIN + 255) / 256, b256, 0, stream>>>(W1, W1t);
    tr_w_kernel<DH><<<(128 * DH + 255) / 256, b256, 0, stream>>>(W2, W2t);

    // ---- layer 1 ----
    mm_bt<DIN, 0, 1, 1><<<gMM, b256, 0, stream>>>(x, W1t, B0b, nullptr, nullptr, nullptr, dinv, Hsb, NNODES);
    gram_gather<<<gGG, b256, 0, stream>>>(B0b, Hsb, dinv, offsets, eidx, P, Sb, NNODES);
    gram_reduce<<<64, b256, 0, stream>>>(P, Gb);
    mm_bt<DH, 1, 0, 0><<<gMM, b256, 0, stream>>>(B0b, Gb, B1b, B0b, Sb, b1, nullptr, nullptr, NNODES);

    // ---- layer 2 ----
    mm_bt<DH, 0, 0, 1><<<gMM, b256, 0, stream>>>(B1b, W2t, B0b, nullptr, nullptr, nullptr, dinv, Hsb, NNODES);
    gram_gather<<<gGG, b256, 0, stream>>>(B0b, Hsb, dinv, offsets, eidx, P, Sb, NNODES);
    gram_reduce<<<64, b256, 0, stream>>>(P, Gb);
    mm_bt<DH, 1, 0, 0><<<gMM, b256, 0, stream>>>(B0b, Gb, B1b, B0b, Sb, b2, nullptr, nullptr, NNODES);

    // ---- fc + log_softmax (MFMA) ----
    fc_mfma<<<gFC, b256, 0, stream>>>(B1b, Wf, bf, out, NNODES);
}